// Round 1
// 259.737 us; speedup vs baseline: 1.0423x; 1.0423x over previous
//
#include <hip/hip_runtime.h>

// ---------------------------------------------------------------------------
// SpatialHead, round 3: latency-tolerant staging everywhere.
// All staging loops are fully unrolled into fixed per-thread roles:
//   phase A issues ALL global loads into registers (1 latency exposure),
//   phase B packs+writes LDS.  coord_conv additionally software-pipelines:
// next cc-chunk's loads are issued before the current chunk's MFMAs, so
// HBM latency hides under compute (T14 async-stage split).
// MFMA 32x32x16_bf16 layouts unchanged; LDS px stride = 72 u16.
// ---------------------------------------------------------------------------

typedef unsigned short u16;
typedef unsigned int u32;
typedef __attribute__((ext_vector_type(8)))  short bf16x8;
typedef __attribute__((ext_vector_type(16))) float f32x16;

#define EPSBN 1e-5f

__device__ __forceinline__ u16 f2bf(float f) {          // RNE fp32->bf16
  u32 u = __builtin_bit_cast(u32, f);
  u32 r = u + 0x7FFFu + ((u >> 16) & 1u);
  return (u16)(r >> 16);
}
__device__ __forceinline__ u32 pk2(float a, float b) {
  return (u32)f2bf(a) | ((u32)f2bf(b) << 16);
}
__device__ __forceinline__ float lo2f(u32 w) { return __builtin_bit_cast(float, w << 16); }
__device__ __forceinline__ float hi2f(u32 w) { return __builtin_bit_cast(float, w & 0xFFFF0000u); }

// ---------------------------------------------------------------------------
// Weight fragment counts (u16):
//  wcf: [cc4][tap9][h4][nt2]*512        = 147456
//  wcc: [tap9][nt2]*512                 = 9216    (coord xx/yy channels)
//  wof: [tap9][h4]*512                  = 18432   (oc padded 18->32, nt=0)
//  wdf/wr1/wr2: [tap9][h4][nt2]*512     = 36864 each
// ---------------------------------------------------------------------------
#define N_WCF 147456
#define N_WCC 9216
#define N_WOF 18432
#define N_W64 36864
#define N_ALLW (N_WCF + N_WCC + N_WOF + 3*N_W64)   // 285696

__global__ __launch_bounds__(256) void prep_kernel(
    const float* __restrict__ coord_w, const float* __restrict__ off_w,
    const float* __restrict__ dc_w, const float* __restrict__ r1_w,
    const float* __restrict__ r2_w,
    u16* __restrict__ wcf, u16* __restrict__ wcc, u16* __restrict__ wof,
    u16* __restrict__ wdf, u16* __restrict__ wr1, u16* __restrict__ wr2)
{
  int i = blockIdx.x * 256 + threadIdx.x;
  if (i >= N_ALLW) return;
  int d = i;
  if (d < N_WCF) {
    int j = d & 7, lane = (d >> 3) & 63, frag = d >> 9;
    int nt = frag & 1, h = (frag >> 1) & 3, tap = (frag >> 3) % 9, cc = (frag >> 3) / 9;
    int ic = cc * 64 + h * 16 + ((lane >> 5) << 3) + j;
    int oc = nt * 32 + (lane & 31);
    wcf[d] = f2bf(coord_w[((size_t)oc * 258 + ic) * 9 + tap]);
    return;
  }
  d -= N_WCF;
  if (d < N_WCC) {
    int j = d & 7, lane = (d >> 3) & 63, frag = d >> 9;
    int nt = frag & 1, tap = frag >> 1;
    int ic = 256 + ((lane >> 5) << 3) + j;
    int oc = nt * 32 + (lane & 31);
    wcc[d] = (ic < 258) ? f2bf(coord_w[((size_t)oc * 258 + ic) * 9 + tap]) : (u16)0;
    return;
  }
  d -= N_WCC;
  if (d < N_WOF) {
    int j = d & 7, lane = (d >> 3) & 63, frag = d >> 9;
    int h = frag & 3, tap = frag >> 2;
    int ic = h * 16 + ((lane >> 5) << 3) + j;
    int oc = lane & 31;
    wof[d] = (oc < 18) ? f2bf(off_w[((size_t)oc * 64 + ic) * 9 + tap]) : (u16)0;
    return;
  }
  d -= N_WOF;
  int seg = d / N_W64;
  int e = d - seg * N_W64;
  int j = e & 7, lane = (e >> 3) & 63, frag = e >> 9;
  int nt = frag & 1, h = (frag >> 1) & 3, tap = frag >> 3;
  int ic = h * 16 + ((lane >> 5) << 3) + j;
  int oc = nt * 32 + (lane & 31);
  const float* src = (seg == 0) ? dc_w : (seg == 1) ? r1_w : r2_w;
  u16* dst = (seg == 0) ? wdf : (seg == 1) ? wr1 : wr2;
  dst[e] = f2bf(src[((size_t)oc * 64 + ic) * 9 + tap]);
}

// ---------------------------------------------------------------------------
// Coord conv 258->64 + BN1 + ReLU -> x1b (bf16 NHWC64).
// Block: 32x4 px tile (M=32 along x), 4 waves = 4 rows, 2 N-tiles each.
// Pipelined: regs(cc+1) loads issued before MFMA(cc).
// ---------------------------------------------------------------------------
__global__ __launch_bounds__(256, 3) void coord_conv_kernel(
    const float* __restrict__ feat, const u16* __restrict__ wcf,
    const u16* __restrict__ wcc, const float* __restrict__ cb,
    const float* __restrict__ g, const float* __restrict__ bb,
    const float* __restrict__ m, const float* __restrict__ v,
    u16* __restrict__ x1b)
{
  __shared__ __align__(16) u16 tile[6 * 34 * 72];  // 29376 B
  const int t = threadIdx.x;
  const int wv = t >> 6, lane = t & 63;
  const int l31 = lane & 31, l5 = lane >> 5;
  const int x0 = blockIdx.x * 32, y0 = blockIdx.y * 4, b = blockIdx.z;

  f32x16 acc[2] = {};
  float4 pa[7], pb[7];

  // issue all 7 role-loads for chunk cc into registers (no waits between)
  auto issue = [&](int cc) {
    #pragma unroll
    for (int r = 0; r < 7; ++r) {
      const int i = t + r * 256;
      const float4 z = {0.f, 0.f, 0.f, 0.f};
      pa[r] = z; pb[r] = z;
      if (i < 1632) {
        const int px = i >> 3, gg = i & 7;
        const int ly = px / 34, lx = px - ly * 34;
        const int gy = y0 + ly - 1, gx = x0 + lx - 1;
        if ((unsigned)gy < 96u && (unsigned)gx < 96u) {
          const float* p = feat + ((size_t)((b * 96 + gy) * 96 + gx)) * 256
                           + cc * 64 + gg * 8;
          pa[r] = *(const float4*)p;
          pb[r] = *(const float4*)(p + 4);
        }
      }
    }
  };
  // pack prefetched registers to bf16 and commit to LDS
  auto commit = [&]() {
    #pragma unroll
    for (int r = 0; r < 7; ++r) {
      const int i = t + r * 256;
      if (i < 1632) {
        const int px = i >> 3, gg = i & 7;
        uint4 o;
        o.x = pk2(pa[r].x, pa[r].y); o.y = pk2(pa[r].z, pa[r].w);
        o.z = pk2(pb[r].x, pb[r].y); o.w = pk2(pb[r].z, pb[r].w);
        *(uint4*)(tile + px * 72 + gg * 8) = o;
      }
    }
  };

  issue(0);
  for (int cc = 0; cc < 4; ++cc) {
    __syncthreads();            // previous chunk's MFMAs done reading LDS
    commit();                   // vmcnt waits happen here
    __syncthreads();
    if (cc < 3) issue(cc + 1);  // next chunk's loads fly during MFMA
    #pragma unroll
    for (int tap = 0; tap < 9; ++tap) {
      const int dy = tap / 3, dx = tap - dy * 3;
      #pragma unroll
      for (int h = 0; h < 4; ++h) {
        const bf16x8 afr = *(const bf16x8*)(tile +
            ((wv + dy) * 34 + l31 + dx) * 72 + h * 16 + l5 * 8);
        #pragma unroll
        for (int nt = 0; nt < 2; ++nt) {
          const bf16x8 bfr = *(const bf16x8*)(wcf +
              ((size_t)((((cc * 9 + tap) * 4 + h) * 2) + nt)) * 512 + lane * 8);
          acc[nt] = __builtin_amdgcn_mfma_f32_32x32x16_bf16(afr, bfr, acc[nt],
                                                            0, 0, 0);
        }
      }
    }
  }

  // coordinate channels: one K=16 step (ch0=xx, ch1=yy, rest 0)
  __syncthreads();
  for (int i = t; i < 408; i += 256) {
    const int px = i >> 1, gg = i & 1;
    const int ly = px / 34, lx = px - ly * 34;
    const int gy = y0 + ly - 1, gx = x0 + lx - 1;
    uint4 o = {0u, 0u, 0u, 0u};
    if (gg == 0 && (unsigned)gy < 96u && (unsigned)gx < 96u) {
      const float xx = -1.f + (2.f / 95.f) * (float)gx;
      const float yy = -1.f + (2.f / 95.f) * (float)gy;
      o.x = pk2(xx, yy);
    }
    *(uint4*)(tile + (ly * 34 + lx) * 72 + gg * 8) = o;
  }
  __syncthreads();
  #pragma unroll
  for (int tap = 0; tap < 9; ++tap) {
    const int dy = tap / 3, dx = tap - dy * 3;
    const bf16x8 afr = *(const bf16x8*)(tile +
        ((wv + dy) * 34 + l31 + dx) * 72 + l5 * 8);
    #pragma unroll
    for (int nt = 0; nt < 2; ++nt) {
      const bf16x8 bfr = *(const bf16x8*)(wcc +
          ((size_t)(tap * 2 + nt)) * 512 + lane * 8);
      acc[nt] = __builtin_amdgcn_mfma_f32_32x32x16_bf16(afr, bfr, acc[nt],
                                                        0, 0, 0);
    }
  }

  // epilogue: BN1 (+conv bias) + ReLU -> bf16
  const int y = y0 + wv;
  #pragma unroll
  for (int nt = 0; nt < 2; ++nt) {
    const int oc = nt * 32 + l31;
    const float inv = g[oc] * rsqrtf(v[oc] + EPSBN);
    const float sh = bb[oc] - m[oc] * inv + cb[oc] * inv;
    #pragma unroll
    for (int r = 0; r < 16; ++r) {
      const int xr = (r & 3) + 8 * (r >> 2) + 4 * l5;
      const float val = fmaxf(fmaf(acc[nt][r], inv, sh), 0.f);
      x1b[((size_t)((b * 96 + y) * 96 + x0 + xr)) * 64 + oc] = f2bf(val);
    }
  }
}

// ---------------------------------------------------------------------------
// 64->64ch 3x3 conv (bf16 NHWC64 in). Block 32x4 px, 4 waves = rows.
// Staging: all 7 role-loads issued before any LDS write.
// ---------------------------------------------------------------------------
template<int NN, int EPI>
__global__ __launch_bounds__(256, 4) void conv64_kernel(
    const u16* __restrict__ xin, const u16* __restrict__ wf,
    const float* __restrict__ bias,
    const float* __restrict__ g, const float* __restrict__ bb,
    const float* __restrict__ m, const float* __restrict__ v,
    const float* __restrict__ ow, const float* __restrict__ ob,
    void* __restrict__ outp)
{
  __shared__ __align__(16) u16 tile[6 * 34 * 72];
  __shared__ float red[128];
  const int t = threadIdx.x;
  const int wv = t >> 6, lane = t & 63;
  const int l31 = lane & 31, l5 = lane >> 5;
  const int x0 = blockIdx.x * 32, y0 = blockIdx.y * 4, b = blockIdx.z;

  uint4 pf[7];
  #pragma unroll
  for (int r = 0; r < 7; ++r) {
    const int i = t + r * 256;
    const uint4 z = {0u, 0u, 0u, 0u};
    pf[r] = z;
    if (i < 1632) {
      const int px = i >> 3, gg = i & 7;
      const int ly = px / 34, lx = px - ly * 34;
      const int gy = y0 + ly - 1, gx = x0 + lx - 1;
      if ((unsigned)gy < 96u && (unsigned)gx < 96u)
        pf[r] = *(const uint4*)(xin + (((size_t)((b * 96 + gy) * 96 + gx)) << 6)
                                + gg * 8);
    }
  }
  #pragma unroll
  for (int r = 0; r < 7; ++r) {
    const int i = t + r * 256;
    if (i < 1632) {
      const int px = i >> 3, gg = i & 7;
      *(uint4*)(tile + px * 72 + gg * 8) = pf[r];
    }
  }
  __syncthreads();

  f32x16 acc[NN] = {};
  #pragma unroll
  for (int tap = 0; tap < 9; ++tap) {
    const int dy = tap / 3, dx = tap - dy * 3;
    #pragma unroll
    for (int h = 0; h < 4; ++h) {
      const bf16x8 afr = *(const bf16x8*)(tile +
          ((wv + dy) * 34 + l31 + dx) * 72 + h * 16 + l5 * 8);
      #pragma unroll
      for (int nt = 0; nt < NN; ++nt) {
        const bf16x8 bfr = *(const bf16x8*)(wf +
            ((size_t)((tap * 4 + h) * NN + nt)) * 512 + lane * 8);
        acc[nt] = __builtin_amdgcn_mfma_f32_32x32x16_bf16(afr, bfr, acc[nt],
                                                          0, 0, 0);
      }
    }
  }

  const int y = y0 + wv;
  if constexpr (EPI == 0) {
    u16* xo = (u16*)outp;
    #pragma unroll
    for (int nt = 0; nt < NN; ++nt) {
      const int oc = nt * 32 + l31;
      const float inv = g[oc] * rsqrtf(v[oc] + EPSBN);
      const float sh = bb[oc] - m[oc] * inv;
      #pragma unroll
      for (int r = 0; r < 16; ++r) {
        const int xr = (r & 3) + 8 * (r >> 2) + 4 * l5;
        const float val = fmaxf(fmaf(acc[nt][r], inv, sh), 0.f);
        xo[((size_t)((b * 96 + y) * 96 + x0 + xr)) * 64 + oc] = f2bf(val);
      }
    }
  } else if constexpr (EPI == 1) {
    float* fo = (float*)outp;
    const int oc = l31;
    if (oc < 18) {
      const float bs = bias[oc];
      #pragma unroll
      for (int r = 0; r < 16; ++r) {
        const int xr = (r & 3) + 8 * (r >> 2) + 4 * l5;
        fo[((size_t)((b * 96 + y) * 96 + x0 + xr)) * 18 + oc] = acc[0][r] + bs;
      }
    }
  } else {  // EPI == 2
    float pr[16];
    #pragma unroll
    for (int r = 0; r < 16; ++r) pr[r] = 0.f;
    #pragma unroll
    for (int nt = 0; nt < NN; ++nt) {
      const int oc = nt * 32 + l31;
      const float inv = g[oc] * rsqrtf(v[oc] + EPSBN);
      const float sh = bb[oc] - m[oc] * inv;
      const float wo = ow[oc];
      #pragma unroll
      for (int r = 0; r < 16; ++r) {
        const float val = fmaxf(fmaf(acc[nt][r], inv, sh), 0.f);
        pr[r] = fmaf(val, wo, pr[r]);
      }
    }
    #pragma unroll
    for (int mask = 1; mask <= 16; mask <<= 1)
      #pragma unroll
      for (int r = 0; r < 16; ++r)
        pr[r] += __shfl_xor(pr[r], mask);
    if (l31 == 0) {
      #pragma unroll
      for (int r = 0; r < 16; ++r) {
        const int xr = (r & 3) + 8 * (r >> 2) + 4 * l5;
        red[wv * 32 + xr] = pr[r];
      }
    }
    __syncthreads();
    if (t < 128) {
      float* fo = (float*)outp;
      const int yy = y0 + (t >> 5), xx = x0 + (t & 31);
      const float val = red[t] + ob[0];
      fo[(size_t)(b * 96 + yy) * 96 + xx] = 1.f / (1.f + expf(-val));
    }
  }
}

// ---------------------------------------------------------------------------
// Deformable conv 64->64 + BN2 + ReLU -> x2b. Block 16x8 px (128), 4 waves
// = 4 M-tiles of 32 px. Per tap: bilinear sample -> bf16 LDS, 4 K-steps.
// Offset staging unrolled (9x256 roles exactly): all loads before writes.
// ---------------------------------------------------------------------------
__global__ __launch_bounds__(256, 4) void deform_kernel(
    const u16* __restrict__ x1b, const float* __restrict__ off,
    const u16* __restrict__ wdf,
    const float* __restrict__ g, const float* __restrict__ bb,
    const float* __restrict__ m, const float* __restrict__ v,
    u16* __restrict__ x2b)
{
  __shared__ __align__(16) u16 s[128 * 72];   // 18432 B
  __shared__ float offs[128 * 18];            // 9216 B
  const int t = threadIdx.x;
  const int wv = t >> 6, lane = t & 63;
  const int l31 = lane & 31, l5 = lane >> 5;
  const int x0 = blockIdx.x * 16, y0 = blockIdx.y * 8, b = blockIdx.z;

  {
    float po[9];
    #pragma unroll
    for (int r = 0; r < 9; ++r) {
      const int i = t + r * 256;
      const int p = i / 18, c = i - p * 18;
      const int gy = y0 + (p >> 4), gx = x0 + (p & 15);
      po[r] = off[((size_t)((b * 96 + gy) * 96 + gx)) * 18 + c];
    }
    #pragma unroll
    for (int r = 0; r < 9; ++r) offs[t + r * 256] = po[r];
  }

  f32x16 acc[2] = {};

  for (int k = 0; k < 9; ++k) {
    __syncthreads();
    #pragma unroll
    for (int rr = 0; rr < 2; ++rr) {  // 512 roles / 256 threads
      const int role = t + rr * 256;
      const int sp = role >> 2, part = role & 3;   // pixel, 16-ch group
      const int sy = y0 + (sp >> 4), sx = x0 + (sp & 15);
      const float oy = offs[sp * 18 + 2 * k];
      const float ox = offs[sp * 18 + 2 * k + 1];
      const float py = (float)(sy + k / 3 - 1) + oy;
      const float px = (float)(sx + k % 3 - 1) + ox;
      const float yf = floorf(py), xf = floorf(px);
      const float fy = py - yf, fx = px - xf;
      const int yi = (int)yf, xi = (int)xf;
      float val[16];
      #pragma unroll
      for (int j = 0; j < 16; ++j) val[j] = 0.f;
      #pragma unroll
      for (int cor = 0; cor < 4; ++cor) {
        const int cy = yi + (cor >> 1), cx = xi + (cor & 1);
        if ((unsigned)cy < 96u && (unsigned)cx < 96u) {
          const float wy = (cor & 2) ? fy : 1.f - fy;
          const float wx = (cor & 1) ? fx : 1.f - fx;
          const float wgt = wy * wx;
          const u16* sp2 = x1b + ((size_t)((b * 96 + cy) * 96 + cx)) * 64
                           + part * 16;
          const uint4 ua = *(const uint4*)sp2;
          const uint4 ub = *(const uint4*)(sp2 + 8);
          const u32 uu[8] = {ua.x, ua.y, ua.z, ua.w, ub.x, ub.y, ub.z, ub.w};
          #pragma unroll
          for (int u = 0; u < 8; ++u) {
            val[2 * u]     = fmaf(wgt, lo2f(uu[u]), val[2 * u]);
            val[2 * u + 1] = fmaf(wgt, hi2f(uu[u]), val[2 * u + 1]);
          }
        }
      }
      u32 pk[8];
      #pragma unroll
      for (int u = 0; u < 8; ++u) pk[u] = pk2(val[2 * u], val[2 * u + 1]);
      uint4 w0 = {pk[0], pk[1], pk[2], pk[3]};
      uint4 w1 = {pk[4], pk[5], pk[6], pk[7]};
      *(uint4*)(s + sp * 72 + part * 16) = w0;
      *(uint4*)(s + sp * 72 + part * 16 + 8) = w1;
    }
    __syncthreads();
    #pragma unroll
    for (int h = 0; h < 4; ++h) {
      const bf16x8 afr = *(const bf16x8*)(s + (wv * 32 + l31) * 72
                                          + h * 16 + l5 * 8);
      #pragma unroll
      for (int nt = 0; nt < 2; ++nt) {
        const bf16x8 bfr = *(const bf16x8*)(wdf +
            ((size_t)((k * 4 + h) * 2 + nt)) * 512 + lane * 8);
        acc[nt] = __builtin_amdgcn_mfma_f32_32x32x16_bf16(afr, bfr, acc[nt],
                                                          0, 0, 0);
      }
    }
  }

  #pragma unroll
  for (int nt = 0; nt < 2; ++nt) {
    const int oc = nt * 32 + l31;
    const float inv = g[oc] * rsqrtf(v[oc] + EPSBN);
    const float sh = bb[oc] - m[oc] * inv;
    #pragma unroll
    for (int r = 0; r < 16; ++r) {
      const int pxi = wv * 32 + (r & 3) + 8 * (r >> 2) + 4 * l5;
      const int y = y0 + (pxi >> 4), x = x0 + (pxi & 15);
      const float val = fmaxf(fmaf(acc[nt][r], inv, sh), 0.f);
      x2b[((size_t)((b * 96 + y) * 96 + x)) * 64 + oc] = f2bf(val);
    }
  }
}

extern "C" void kernel_launch(void* const* d_in, const int* in_sizes, int n_in,
                              void* d_out, int out_size, void* d_ws,
                              size_t ws_size, hipStream_t stream)
{
  (void)in_sizes; (void)n_in; (void)out_size; (void)ws_size;
  const float* features = (const float*)d_in[0];
  const float* coord_w  = (const float*)d_in[1];
  const float* coord_b  = (const float*)d_in[2];
  const float* bn1g = (const float*)d_in[3];
  const float* bn1b = (const float*)d_in[4];
  const float* bn1m = (const float*)d_in[5];
  const float* bn1v = (const float*)d_in[6];
  const float* off_w = (const float*)d_in[7];
  const float* off_b = (const float*)d_in[8];
  const float* dc_w  = (const float*)d_in[9];
  const float* bn2g = (const float*)d_in[10];
  const float* bn2b = (const float*)d_in[11];
  const float* bn2m = (const float*)d_in[12];
  const float* bn2v = (const float*)d_in[13];
  const float* r1_w = (const float*)d_in[14];
  const float* bn3g = (const float*)d_in[15];
  const float* bn3b = (const float*)d_in[16];
  const float* bn3m = (const float*)d_in[17];
  const float* bn3v = (const float*)d_in[18];
  const float* r2_w = (const float*)d_in[19];
  const float* bn4g = (const float*)d_in[20];
  const float* bn4b = (const float*)d_in[21];
  const float* bn4m = (const float*)d_in[22];
  const float* bn4v = (const float*)d_in[23];
  const float* out_w = (const float*)d_in[24];
  const float* out_b = (const float*)d_in[25];

  char* W = (char*)d_ws;
  float* offb = (float*)W;                         //  5,308,416 B
  u16*   x1b  = (u16*)(W + 5308416);               //  9,437,184 B
  u16*   x2b  = (u16*)(W + 14745600);
  u16*   x3b  = (u16*)(W + 24182784);
  u16*   wcf  = (u16*)(W + 33619968);
  u16*   wcc  = wcf + N_WCF;
  u16*   wof  = wcc + N_WCC;
  u16*   wdf  = wof + N_WOF;
  u16*   wr1  = wdf + N_W64;
  u16*   wr2  = wr1 + N_W64;

  prep_kernel<<<(N_ALLW + 255) / 256, 256, 0, stream>>>(
      coord_w, off_w, dc_w, r1_w, r2_w, wcf, wcc, wof, wdf, wr1, wr2);

  dim3 grid(3, 24, 8);   // 32x4 tiles
  dim3 gridD(6, 12, 8);  // 16x8 tiles (deform)

  coord_conv_kernel<<<grid, 256, 0, stream>>>(
      features, wcf, wcc, coord_b, bn1g, bn1b, bn1m, bn1v, x1b);
  conv64_kernel<1, 1><<<grid, 256, 0, stream>>>(
      x1b, wof, off_b, nullptr, nullptr, nullptr, nullptr, nullptr, nullptr,
      (void*)offb);
  deform_kernel<<<gridD, 256, 0, stream>>>(
      x1b, offb, wdf, bn2g, bn2b, bn2m, bn2v, x2b);
  conv64_kernel<2, 0><<<grid, 256, 0, stream>>>(
      x2b, wr1, nullptr, bn3g, bn3b, bn3m, bn3v, nullptr, nullptr, (void*)x3b);
  conv64_kernel<2, 2><<<grid, 256, 0, stream>>>(
      x3b, wr2, nullptr, bn4g, bn4b, bn4m, bn4v, out_w, out_b, d_out);
}

// Round 2
// 252.615 us; speedup vs baseline: 1.0717x; 1.0282x over previous
//
#include <hip/hip_runtime.h>

// ---------------------------------------------------------------------------
// SpatialHead, round 4: 512-thread / 8-wave blocks everywhere.
// Waves split the oc (N) dimension: wave = (row, ntw); each wave owns ONE
// 32-oc tile -> acc is a single f32x16 (16 VGPR), per-wave MFMA chain
// halves, waves/CU doubles (~9 -> ~18).  Deform double-buffers the sample
// tile and issues tap k+1's gathers before tap k's MFMAs (T14 split).
// conv64<1,*> (32 padded oc) splits K-halves across wave pairs + LDS reduce.
// MFMA 32x32x16_bf16 layouts unchanged; LDS px stride = 72 u16.
// ---------------------------------------------------------------------------

typedef unsigned short u16;
typedef unsigned int u32;
typedef __attribute__((ext_vector_type(8)))  short bf16x8;
typedef __attribute__((ext_vector_type(16))) float f32x16;

#define EPSBN 1e-5f

__device__ __forceinline__ u16 f2bf(float f) {          // RNE fp32->bf16
  u32 u = __builtin_bit_cast(u32, f);
  u32 r = u + 0x7FFFu + ((u >> 16) & 1u);
  return (u16)(r >> 16);
}
__device__ __forceinline__ u32 pk2(float a, float b) {
  return (u32)f2bf(a) | ((u32)f2bf(b) << 16);
}
__device__ __forceinline__ float lo2f(u32 w) { return __builtin_bit_cast(float, w << 16); }
__device__ __forceinline__ float hi2f(u32 w) { return __builtin_bit_cast(float, w & 0xFFFF0000u); }

// ---------------------------------------------------------------------------
// Weight fragment counts (u16):
//  wcf: [cc4][tap9][h4][nt2]*512        = 147456
//  wcc: [tap9][nt2]*512                 = 9216    (coord xx/yy channels)
//  wof: [tap9][h4]*512                  = 18432   (oc padded 18->32, nt=0)
//  wdf/wr1/wr2: [tap9][h4][nt2]*512     = 36864 each
// ---------------------------------------------------------------------------
#define N_WCF 147456
#define N_WCC 9216
#define N_WOF 18432
#define N_W64 36864
#define N_ALLW (N_WCF + N_WCC + N_WOF + 3*N_W64)   // 285696

__global__ __launch_bounds__(256) void prep_kernel(
    const float* __restrict__ coord_w, const float* __restrict__ off_w,
    const float* __restrict__ dc_w, const float* __restrict__ r1_w,
    const float* __restrict__ r2_w,
    u16* __restrict__ wcf, u16* __restrict__ wcc, u16* __restrict__ wof,
    u16* __restrict__ wdf, u16* __restrict__ wr1, u16* __restrict__ wr2)
{
  int i = blockIdx.x * 256 + threadIdx.x;
  if (i >= N_ALLW) return;
  int d = i;
  if (d < N_WCF) {
    int j = d & 7, lane = (d >> 3) & 63, frag = d >> 9;
    int nt = frag & 1, h = (frag >> 1) & 3, tap = (frag >> 3) % 9, cc = (frag >> 3) / 9;
    int ic = cc * 64 + h * 16 + ((lane >> 5) << 3) + j;
    int oc = nt * 32 + (lane & 31);
    wcf[d] = f2bf(coord_w[((size_t)oc * 258 + ic) * 9 + tap]);
    return;
  }
  d -= N_WCF;
  if (d < N_WCC) {
    int j = d & 7, lane = (d >> 3) & 63, frag = d >> 9;
    int nt = frag & 1, tap = frag >> 1;
    int ic = 256 + ((lane >> 5) << 3) + j;
    int oc = nt * 32 + (lane & 31);
    wcc[d] = (ic < 258) ? f2bf(coord_w[((size_t)oc * 258 + ic) * 9 + tap]) : (u16)0;
    return;
  }
  d -= N_WCC;
  if (d < N_WOF) {
    int j = d & 7, lane = (d >> 3) & 63, frag = d >> 9;
    int h = frag & 3, tap = frag >> 2;
    int ic = h * 16 + ((lane >> 5) << 3) + j;
    int oc = lane & 31;
    wof[d] = (oc < 18) ? f2bf(off_w[((size_t)oc * 64 + ic) * 9 + tap]) : (u16)0;
    return;
  }
  d -= N_WOF;
  int seg = d / N_W64;
  int e = d - seg * N_W64;
  int j = e & 7, lane = (e >> 3) & 63, frag = e >> 9;
  int nt = frag & 1, h = (frag >> 1) & 3, tap = frag >> 3;
  int ic = h * 16 + ((lane >> 5) << 3) + j;
  int oc = nt * 32 + (lane & 31);
  const float* src = (seg == 0) ? dc_w : (seg == 1) ? r1_w : r2_w;
  u16* dst = (seg == 0) ? wdf : (seg == 1) ? wr1 : wr2;
  dst[e] = f2bf(src[((size_t)oc * 64 + ic) * 9 + tap]);
}

// ---------------------------------------------------------------------------
// Coord conv 258->64 + BN1 + ReLU -> x1b (bf16 NHWC64).
// Block: 32x4 px, 512 threads, 8 waves = (row 0..3) x (ntw 0..1).
// Pipelined fp32 staging: regs(cc+1) loads issued before MFMA(cc).
// ---------------------------------------------------------------------------
__global__ __launch_bounds__(512, 4) void coord_conv_kernel(
    const float* __restrict__ feat, const u16* __restrict__ wcf,
    const u16* __restrict__ wcc, const float* __restrict__ cb,
    const float* __restrict__ g, const float* __restrict__ bb,
    const float* __restrict__ m, const float* __restrict__ v,
    u16* __restrict__ x1b)
{
  __shared__ __align__(16) u16 tile[6 * 34 * 72];  // 29376 B
  const int t = threadIdx.x;
  const int wv = t >> 6, lane = t & 63;
  const int l31 = lane & 31, l5 = lane >> 5;
  const int row = wv & 3, ntw = wv >> 2;
  const int x0 = blockIdx.x * 32, y0 = blockIdx.y * 4, b = blockIdx.z;

  f32x16 acc = {};
  float4 pa[4], pb[4];

  auto issue = [&](int cc) {
    #pragma unroll
    for (int r = 0; r < 4; ++r) {
      const int i = t + r * 512;
      const float4 z = {0.f, 0.f, 0.f, 0.f};
      pa[r] = z; pb[r] = z;
      if (i < 1632) {
        const int px = i >> 3, gg = i & 7;
        const int ly = px / 34, lx = px - ly * 34;
        const int gy = y0 + ly - 1, gx = x0 + lx - 1;
        if ((unsigned)gy < 96u && (unsigned)gx < 96u) {
          const float* p = feat + ((size_t)((b * 96 + gy) * 96 + gx)) * 256
                           + cc * 64 + gg * 8;
          pa[r] = *(const float4*)p;
          pb[r] = *(const float4*)(p + 4);
        }
      }
    }
  };
  auto commit = [&]() {
    #pragma unroll
    for (int r = 0; r < 4; ++r) {
      const int i = t + r * 512;
      if (i < 1632) {
        const int px = i >> 3, gg = i & 7;
        uint4 o;
        o.x = pk2(pa[r].x, pa[r].y); o.y = pk2(pa[r].z, pa[r].w);
        o.z = pk2(pb[r].x, pb[r].y); o.w = pk2(pb[r].z, pb[r].w);
        *(uint4*)(tile + px * 72 + gg * 8) = o;
      }
    }
  };

  issue(0);
  for (int cc = 0; cc < 4; ++cc) {
    __syncthreads();
    commit();
    __syncthreads();
    if (cc < 3) issue(cc + 1);
    #pragma unroll
    for (int tap = 0; tap < 9; ++tap) {
      const int dy = tap / 3, dx = tap - dy * 3;
      #pragma unroll
      for (int h = 0; h < 4; ++h) {
        const bf16x8 afr = *(const bf16x8*)(tile +
            ((row + dy) * 34 + l31 + dx) * 72 + h * 16 + l5 * 8);
        const bf16x8 bfr = *(const bf16x8*)(wcf +
            ((size_t)((((cc * 9 + tap) * 4 + h) * 2) + ntw)) * 512 + lane * 8);
        acc = __builtin_amdgcn_mfma_f32_32x32x16_bf16(afr, bfr, acc, 0, 0, 0);
      }
    }
  }

  // coordinate channels: one K=16 step (ch0=xx, ch1=yy, rest 0)
  __syncthreads();
  for (int i = t; i < 408; i += 512) {
    const int px = i >> 1, gg = i & 1;
    const int ly = px / 34, lx = px - ly * 34;
    const int gy = y0 + ly - 1, gx = x0 + lx - 1;
    uint4 o = {0u, 0u, 0u, 0u};
    if (gg == 0 && (unsigned)gy < 96u && (unsigned)gx < 96u) {
      const float xx = -1.f + (2.f / 95.f) * (float)gx;
      const float yy = -1.f + (2.f / 95.f) * (float)gy;
      o.x = pk2(xx, yy);
    }
    *(uint4*)(tile + (ly * 34 + lx) * 72 + gg * 8) = o;
  }
  __syncthreads();
  #pragma unroll
  for (int tap = 0; tap < 9; ++tap) {
    const int dy = tap / 3, dx = tap - dy * 3;
    const bf16x8 afr = *(const bf16x8*)(tile +
        ((row + dy) * 34 + l31 + dx) * 72 + l5 * 8);
    const bf16x8 bfr = *(const bf16x8*)(wcc +
        ((size_t)(tap * 2 + ntw)) * 512 + lane * 8);
    acc = __builtin_amdgcn_mfma_f32_32x32x16_bf16(afr, bfr, acc, 0, 0, 0);
  }

  // epilogue: BN1 (+conv bias) + ReLU -> bf16
  const int y = y0 + row;
  const int oc = ntw * 32 + l31;
  const float inv = g[oc] * rsqrtf(v[oc] + EPSBN);
  const float sh = bb[oc] - m[oc] * inv + cb[oc] * inv;
  #pragma unroll
  for (int r = 0; r < 16; ++r) {
    const int xr = (r & 3) + 8 * (r >> 2) + 4 * l5;
    const float val = fmaxf(fmaf(acc[r], inv, sh), 0.f);
    x1b[((size_t)((b * 96 + y) * 96 + x0 + xr)) * 64 + oc] = f2bf(val);
  }
}

// ---------------------------------------------------------------------------
// 64->64ch 3x3 conv (bf16 NHWC64 in). Block 32x4 px, 512 threads, 8 waves.
// NN==2: wave pairs split oc tiles.  NN==1 (offset conv, 32 padded oc):
// wave pairs split K-halves (h 0-1 vs 2-3), LDS reduce, ntw=0 writes.
// EPI: 0 = BN+ReLU -> bf16 ; 1 = +bias -> fp32 NHWC18 ; 2 = BN+ReLU +
// 1x1 out conv + sigmoid -> fp32 (B,96,96), cross-wave-pair add in LDS.
// ---------------------------------------------------------------------------
template<int NN, int EPI>
__global__ __launch_bounds__(512, 4) void conv64_kernel(
    const u16* __restrict__ xin, const u16* __restrict__ wf,
    const float* __restrict__ bias,
    const float* __restrict__ g, const float* __restrict__ bb,
    const float* __restrict__ m, const float* __restrict__ v,
    const float* __restrict__ ow, const float* __restrict__ ob,
    void* __restrict__ outp)
{
  __shared__ __align__(16) u16 tile[6 * 34 * 72];
  __shared__ float red[2][128];
  const int t = threadIdx.x;
  const int wv = t >> 6, lane = t & 63;
  const int l31 = lane & 31, l5 = lane >> 5;
  const int row = wv & 3, ntw = wv >> 2;
  const int x0 = blockIdx.x * 32, y0 = blockIdx.y * 4, b = blockIdx.z;

  uint4 pf[4];
  #pragma unroll
  for (int r = 0; r < 4; ++r) {
    const int i = t + r * 512;
    const uint4 z = {0u, 0u, 0u, 0u};
    pf[r] = z;
    if (i < 1632) {
      const int px = i >> 3, gg = i & 7;
      const int ly = px / 34, lx = px - ly * 34;
      const int gy = y0 + ly - 1, gx = x0 + lx - 1;
      if ((unsigned)gy < 96u && (unsigned)gx < 96u)
        pf[r] = *(const uint4*)(xin + (((size_t)((b * 96 + gy) * 96 + gx)) << 6)
                                + gg * 8);
    }
  }
  #pragma unroll
  for (int r = 0; r < 4; ++r) {
    const int i = t + r * 512;
    if (i < 1632) {
      const int px = i >> 3, gg = i & 7;
      *(uint4*)(tile + px * 72 + gg * 8) = pf[r];
    }
  }
  __syncthreads();

  f32x16 acc = {};
  #pragma unroll
  for (int tap = 0; tap < 9; ++tap) {
    const int dy = tap / 3, dx = tap - dy * 3;
    if constexpr (NN == 2) {
      #pragma unroll
      for (int h = 0; h < 4; ++h) {
        const bf16x8 afr = *(const bf16x8*)(tile +
            ((row + dy) * 34 + l31 + dx) * 72 + h * 16 + l5 * 8);
        const bf16x8 bfr = *(const bf16x8*)(wf +
            ((size_t)((tap * 4 + h) * 2 + ntw)) * 512 + lane * 8);
        acc = __builtin_amdgcn_mfma_f32_32x32x16_bf16(afr, bfr, acc, 0, 0, 0);
      }
    } else {
      #pragma unroll
      for (int hh = 0; hh < 2; ++hh) {
        const int h = ntw * 2 + hh;
        const bf16x8 afr = *(const bf16x8*)(tile +
            ((row + dy) * 34 + l31 + dx) * 72 + h * 16 + l5 * 8);
        const bf16x8 bfr = *(const bf16x8*)(wf +
            ((size_t)(tap * 4 + h)) * 512 + lane * 8);
        acc = __builtin_amdgcn_mfma_f32_32x32x16_bf16(afr, bfr, acc, 0, 0, 0);
      }
    }
  }

  const int y = y0 + row;
  if constexpr (EPI == 0) {
    u16* xo = (u16*)outp;
    const int oc = ntw * 32 + l31;
    const float inv = g[oc] * rsqrtf(v[oc] + EPSBN);
    const float sh = bb[oc] - m[oc] * inv;
    #pragma unroll
    for (int r = 0; r < 16; ++r) {
      const int xr = (r & 3) + 8 * (r >> 2) + 4 * l5;
      const float val = fmaxf(fmaf(acc[r], inv, sh), 0.f);
      xo[((size_t)((b * 96 + y) * 96 + x0 + xr)) * 64 + oc] = f2bf(val);
    }
  } else if constexpr (EPI == 1) {
    // K-halves: combine ntw=1 partials into ntw=0 via LDS (tile is dead)
    __syncthreads();
    float* redk = (float*)tile;   // 16*256 floats = 16 KB <= tile
    if (ntw == 1) {
      #pragma unroll
      for (int r = 0; r < 16; ++r)
        redk[r * 256 + row * 64 + lane] = acc[r];
    }
    __syncthreads();
    if (ntw == 0) {
      #pragma unroll
      for (int r = 0; r < 16; ++r)
        acc[r] += redk[r * 256 + row * 64 + lane];
      float* fo = (float*)outp;
      const int oc = l31;
      if (oc < 18) {
        const float bs = bias[oc];
        #pragma unroll
        for (int r = 0; r < 16; ++r) {
          const int xr = (r & 3) + 8 * (r >> 2) + 4 * l5;
          fo[((size_t)((b * 96 + y) * 96 + x0 + xr)) * 18 + oc] = acc[r] + bs;
        }
      }
    }
  } else {  // EPI == 2
    float pr[16];
    #pragma unroll
    for (int r = 0; r < 16; ++r) pr[r] = 0.f;
    {
      const int oc = ntw * 32 + l31;
      const float inv = g[oc] * rsqrtf(v[oc] + EPSBN);
      const float sh = bb[oc] - m[oc] * inv;
      const float wo = ow[oc];
      #pragma unroll
      for (int r = 0; r < 16; ++r) {
        const float val = fmaxf(fmaf(acc[r], inv, sh), 0.f);
        pr[r] = fmaf(val, wo, pr[r]);
      }
    }
    #pragma unroll
    for (int mask = 1; mask <= 16; mask <<= 1)
      #pragma unroll
      for (int r = 0; r < 16; ++r)
        pr[r] += __shfl_xor(pr[r], mask);
    if (l31 == 0) {
      #pragma unroll
      for (int r = 0; r < 16; ++r) {
        const int xr = (r & 3) + 8 * (r >> 2) + 4 * l5;
        red[ntw][row * 32 + xr] = pr[r];
      }
    }
    __syncthreads();
    if (t < 128) {
      float* fo = (float*)outp;
      const int yy = y0 + (t >> 5), xx = x0 + (t & 31);
      const float val = red[0][t] + red[1][t] + ob[0];
      fo[(size_t)(b * 96 + yy) * 96 + xx] = 1.f / (1.f + expf(-val));
    }
  }
}

// ---------------------------------------------------------------------------
// Deformable conv 64->64 + BN2 + ReLU -> x2b. Block 16x8 px, 512 threads,
// 8 waves = (mt 0..3: 32-px M tile) x (ntw 0..1: oc tile).
// Double-buffered sample LDS; tap k+1 gathers issued before tap k MFMAs.
// ---------------------------------------------------------------------------
__global__ __launch_bounds__(512, 4) void deform_kernel(
    const u16* __restrict__ x1b, const float* __restrict__ off,
    const u16* __restrict__ wdf,
    const float* __restrict__ g, const float* __restrict__ bb,
    const float* __restrict__ m, const float* __restrict__ v,
    u16* __restrict__ x2b)
{
  __shared__ __align__(16) u16 s[2 * 128 * 72];   // 36864 B
  __shared__ float offs[128 * 18];                //  9216 B
  const int t = threadIdx.x;
  const int wv = t >> 6, lane = t & 63;
  const int l31 = lane & 31, l5 = lane >> 5;
  const int mt = wv & 3, ntw = wv >> 2;
  const int x0 = blockIdx.x * 16, y0 = blockIdx.y * 8, b = blockIdx.z;

  {
    float po[5];
    #pragma unroll
    for (int r = 0; r < 5; ++r) {
      const int i = t + r * 512;
      po[r] = 0.f;
      if (i < 2304) {
        const int p = i / 18, c = i - p * 18;
        const int gy = y0 + (p >> 4), gx = x0 + (p & 15);
        po[r] = off[((size_t)((b * 96 + gy) * 96 + gx)) * 18 + c];
      }
    }
    #pragma unroll
    for (int r = 0; r < 5; ++r) {
      const int i = t + r * 512;
      if (i < 2304) offs[i] = po[r];
    }
  }
  __syncthreads();

  const int sp = t >> 2, part = t & 3;
  const int sy = y0 + (sp >> 4), sx = x0 + (sp & 15);

  uint4 gbuf[8];
  float w4[4];

  auto prefetch = [&](int k) {
    const float oy = offs[sp * 18 + 2 * k];
    const float ox = offs[sp * 18 + 2 * k + 1];
    const float py = (float)(sy + k / 3 - 1) + oy;
    const float px = (float)(sx + k % 3 - 1) + ox;
    const float yf = floorf(py), xf = floorf(px);
    const float fy = py - yf, fx = px - xf;
    const int yi = (int)yf, xi = (int)xf;
    #pragma unroll
    for (int cor = 0; cor < 4; ++cor) {
      const int cy = yi + (cor >> 1), cx = xi + (cor & 1);
      const uint4 z = {0u, 0u, 0u, 0u};
      gbuf[2 * cor] = z; gbuf[2 * cor + 1] = z;
      const float wy = (cor & 2) ? fy : 1.f - fy;
      const float wx = (cor & 1) ? fx : 1.f - fx;
      w4[cor] = 0.f;
      if ((unsigned)cy < 96u && (unsigned)cx < 96u) {
        w4[cor] = wy * wx;
        const u16* p = x1b + ((size_t)((b * 96 + cy) * 96 + cx)) * 64
                       + part * 16;
        gbuf[2 * cor]     = *(const uint4*)p;
        gbuf[2 * cor + 1] = *(const uint4*)(p + 8);
      }
    }
  };
  auto combine = [&](u16* dst) {
    float val[16];
    #pragma unroll
    for (int j = 0; j < 16; ++j) val[j] = 0.f;
    #pragma unroll
    for (int cor = 0; cor < 4; ++cor) {
      const float wgt = w4[cor];
      const u32 uu[8] = {gbuf[2 * cor].x, gbuf[2 * cor].y,
                         gbuf[2 * cor].z, gbuf[2 * cor].w,
                         gbuf[2 * cor + 1].x, gbuf[2 * cor + 1].y,
                         gbuf[2 * cor + 1].z, gbuf[2 * cor + 1].w};
      #pragma unroll
      for (int u = 0; u < 8; ++u) {
        val[2 * u]     = fmaf(wgt, lo2f(uu[u]), val[2 * u]);
        val[2 * u + 1] = fmaf(wgt, hi2f(uu[u]), val[2 * u + 1]);
      }
    }
    u32 pk[8];
    #pragma unroll
    for (int u = 0; u < 8; ++u) pk[u] = pk2(val[2 * u], val[2 * u + 1]);
    uint4 w0 = {pk[0], pk[1], pk[2], pk[3]};
    uint4 w1 = {pk[4], pk[5], pk[6], pk[7]};
    *(uint4*)(dst + sp * 72 + part * 16) = w0;
    *(uint4*)(dst + sp * 72 + part * 16 + 8) = w1;
  };

  f32x16 acc = {};

  prefetch(0);
  combine(s);          // buffer 0
  __syncthreads();

  for (int k = 0; k < 9; ++k) {
    u16* cur = s + (k & 1) * 9216;
    if (k < 8) prefetch(k + 1);          // gathers fly during MFMAs
    #pragma unroll
    for (int h = 0; h < 4; ++h) {
      const bf16x8 afr = *(const bf16x8*)(cur + (mt * 32 + l31) * 72
                                          + h * 16 + l5 * 8);
      const bf16x8 bfr = *(const bf16x8*)(wdf +
          ((size_t)((k * 4 + h) * 2 + ntw)) * 512 + lane * 8);
      acc = __builtin_amdgcn_mfma_f32_32x32x16_bf16(afr, bfr, acc, 0, 0, 0);
    }
    if (k < 8) combine(s + ((k + 1) & 1) * 9216);
    __syncthreads();
  }

  const int oc = ntw * 32 + l31;
  const float inv = g[oc] * rsqrtf(v[oc] + EPSBN);
  const float sh = bb[oc] - m[oc] * inv;
  #pragma unroll
  for (int r = 0; r < 16; ++r) {
    const int pxi = mt * 32 + (r & 3) + 8 * (r >> 2) + 4 * l5;
    const int y = y0 + (pxi >> 4), x = x0 + (pxi & 15);
    const float val = fmaxf(fmaf(acc[r], inv, sh), 0.f);
    x2b[((size_t)((b * 96 + y) * 96 + x)) * 64 + oc] = f2bf(val);
  }
}

extern "C" void kernel_launch(void* const* d_in, const int* in_sizes, int n_in,
                              void* d_out, int out_size, void* d_ws,
                              size_t ws_size, hipStream_t stream)
{
  (void)in_sizes; (void)n_in; (void)out_size; (void)ws_size;
  const float* features = (const float*)d_in[0];
  const float* coord_w  = (const float*)d_in[1];
  const float* coord_b  = (const float*)d_in[2];
  const float* bn1g = (const float*)d_in[3];
  const float* bn1b = (const float*)d_in[4];
  const float* bn1m = (const float*)d_in[5];
  const float* bn1v = (const float*)d_in[6];
  const float* off_w = (const float*)d_in[7];
  const float* off_b = (const float*)d_in[8];
  const float* dc_w  = (const float*)d_in[9];
  const float* bn2g = (const float*)d_in[10];
  const float* bn2b = (const float*)d_in[11];
  const float* bn2m = (const float*)d_in[12];
  const float* bn2v = (const float*)d_in[13];
  const float* r1_w = (const float*)d_in[14];
  const float* bn3g = (const float*)d_in[15];
  const float* bn3b = (const float*)d_in[16];
  const float* bn3m = (const float*)d_in[17];
  const float* bn3v = (const float*)d_in[18];
  const float* r2_w = (const float*)d_in[19];
  const float* bn4g = (const float*)d_in[20];
  const float* bn4b = (const float*)d_in[21];
  const float* bn4m = (const float*)d_in[22];
  const float* bn4v = (const float*)d_in[23];
  const float* out_w = (const float*)d_in[24];
  const float* out_b = (const float*)d_in[25];

  char* W = (char*)d_ws;
  float* offb = (float*)W;                         //  5,308,416 B
  u16*   x1b  = (u16*)(W + 5308416);               //  9,437,184 B
  u16*   x2b  = (u16*)(W + 14745600);
  u16*   x3b  = (u16*)(W + 24182784);
  u16*   wcf  = (u16*)(W + 33619968);
  u16*   wcc  = wcf + N_WCF;
  u16*   wof  = wcc + N_WCC;
  u16*   wdf  = wof + N_WOF;
  u16*   wr1  = wdf + N_W64;
  u16*   wr2  = wr1 + N_W64;

  prep_kernel<<<(N_ALLW + 255) / 256, 256, 0, stream>>>(
      coord_w, off_w, dc_w, r1_w, r2_w, wcf, wcc, wof, wdf, wr1, wr2);

  dim3 grid(3, 24, 8);   // 32x4 tiles
  dim3 gridD(6, 12, 8);  // 16x8 tiles (deform)

  coord_conv_kernel<<<grid, 512, 0, stream>>>(
      features, wcf, wcc, coord_b, bn1g, bn1b, bn1m, bn1v, x1b);
  conv64_kernel<1, 1><<<grid, 512, 0, stream>>>(
      x1b, wof, off_b, nullptr, nullptr, nullptr, nullptr, nullptr, nullptr,
      (void*)offb);
  deform_kernel<<<gridD, 512, 0, stream>>>(
      x1b, offb, wdf, bn2g, bn2b, bn2m, bn2v, x2b);
  conv64_kernel<2, 0><<<grid, 512, 0, stream>>>(
      x2b, wr1, nullptr, bn3g, bn3b, bn3m, bn3v, nullptr, nullptr, (void*)x3b);
  conv64_kernel<2, 2><<<grid, 512, 0, stream>>>(
      x3b, wr2, nullptr, bn4g, bn4b, bn4m, bn4v, out_w, out_b, d_out);
}

// Round 3
// 247.712 us; speedup vs baseline: 1.0929x; 1.0198x over previous
//
#include <hip/hip_runtime.h>

// ---------------------------------------------------------------------------
// SpatialHead, round 5: kill the per-MFMA global weight loads.
// conv-style kernels: waves = (row-pair rp, oc-tile ntw, K-half kh).
//  - 2 rows/wave (acc[2]) -> each weight frag feeds 2 MFMAs (traffic /2)
//  - kh splits the 4 h-subtiles -> 18 frags/wave, batch-preloaded into
//    REGISTERS (one L2 latency per chunk instead of per-MFMA)
//  - kh partial sums reduced through LDS (reusing the dead input tile)
// deform unchanged from round 4.
// MFMA 32x32x16_bf16 layouts unchanged; LDS px stride = 72 u16.
// ---------------------------------------------------------------------------

typedef unsigned short u16;
typedef unsigned int u32;
typedef __attribute__((ext_vector_type(8)))  short bf16x8;
typedef __attribute__((ext_vector_type(16))) float f32x16;

#define EPSBN 1e-5f

__device__ __forceinline__ u16 f2bf(float f) {          // RNE fp32->bf16
  u32 u = __builtin_bit_cast(u32, f);
  u32 r = u + 0x7FFFu + ((u >> 16) & 1u);
  return (u16)(r >> 16);
}
__device__ __forceinline__ u32 pk2(float a, float b) {
  return (u32)f2bf(a) | ((u32)f2bf(b) << 16);
}
__device__ __forceinline__ float lo2f(u32 w) { return __builtin_bit_cast(float, w << 16); }
__device__ __forceinline__ float hi2f(u32 w) { return __builtin_bit_cast(float, w & 0xFFFF0000u); }

// ---------------------------------------------------------------------------
// Weight fragment counts (u16):
//  wcf: [cc4][tap9][h4][nt2]*512        = 147456
//  wcc: [tap9][nt2]*512                 = 9216    (coord xx/yy channels)
//  wof: [tap9][h4]*512                  = 18432   (oc padded 18->32, nt=0)
//  wdf/wr1/wr2: [tap9][h4][nt2]*512     = 36864 each
// ---------------------------------------------------------------------------
#define N_WCF 147456
#define N_WCC 9216
#define N_WOF 18432
#define N_W64 36864
#define N_ALLW (N_WCF + N_WCC + N_WOF + 3*N_W64)   // 285696

__global__ __launch_bounds__(256) void prep_kernel(
    const float* __restrict__ coord_w, const float* __restrict__ off_w,
    const float* __restrict__ dc_w, const float* __restrict__ r1_w,
    const float* __restrict__ r2_w,
    u16* __restrict__ wcf, u16* __restrict__ wcc, u16* __restrict__ wof,
    u16* __restrict__ wdf, u16* __restrict__ wr1, u16* __restrict__ wr2)
{
  int i = blockIdx.x * 256 + threadIdx.x;
  if (i >= N_ALLW) return;
  int d = i;
  if (d < N_WCF) {
    int j = d & 7, lane = (d >> 3) & 63, frag = d >> 9;
    int nt = frag & 1, h = (frag >> 1) & 3, tap = (frag >> 3) % 9, cc = (frag >> 3) / 9;
    int ic = cc * 64 + h * 16 + ((lane >> 5) << 3) + j;
    int oc = nt * 32 + (lane & 31);
    wcf[d] = f2bf(coord_w[((size_t)oc * 258 + ic) * 9 + tap]);
    return;
  }
  d -= N_WCF;
  if (d < N_WCC) {
    int j = d & 7, lane = (d >> 3) & 63, frag = d >> 9;
    int nt = frag & 1, tap = frag >> 1;
    int ic = 256 + ((lane >> 5) << 3) + j;
    int oc = nt * 32 + (lane & 31);
    wcc[d] = (ic < 258) ? f2bf(coord_w[((size_t)oc * 258 + ic) * 9 + tap]) : (u16)0;
    return;
  }
  d -= N_WCC;
  if (d < N_WOF) {
    int j = d & 7, lane = (d >> 3) & 63, frag = d >> 9;
    int h = frag & 3, tap = frag >> 2;
    int ic = h * 16 + ((lane >> 5) << 3) + j;
    int oc = lane & 31;
    wof[d] = (oc < 18) ? f2bf(off_w[((size_t)oc * 64 + ic) * 9 + tap]) : (u16)0;
    return;
  }
  d -= N_WOF;
  int seg = d / N_W64;
  int e = d - seg * N_W64;
  int j = e & 7, lane = (e >> 3) & 63, frag = e >> 9;
  int nt = frag & 1, h = (frag >> 1) & 3, tap = frag >> 3;
  int ic = h * 16 + ((lane >> 5) << 3) + j;
  int oc = nt * 32 + (lane & 31);
  const float* src = (seg == 0) ? dc_w : (seg == 1) ? r1_w : r2_w;
  u16* dst = (seg == 0) ? wdf : (seg == 1) ? wr1 : wr2;
  dst[e] = f2bf(src[((size_t)oc * 64 + ic) * 9 + tap]);
}

// ---------------------------------------------------------------------------
// Coord conv 258->64 + BN1 + ReLU -> x1b (bf16 NHWC64).
// Block 32x4 px, 512 thr, 8 waves = (rp 0..1: row pair) x (ntw: oc tile)
// x (kh: h-half).  18 weight frags/wave/cc batch-preloaded to registers.
// ---------------------------------------------------------------------------
__global__ __launch_bounds__(512, 2) void coord_conv_kernel(
    const float* __restrict__ feat, const u16* __restrict__ wcf,
    const u16* __restrict__ wcc, const float* __restrict__ cb,
    const float* __restrict__ g, const float* __restrict__ bb,
    const float* __restrict__ m, const float* __restrict__ v,
    u16* __restrict__ x1b)
{
  __shared__ __align__(16) u16 tile[6 * 34 * 72];  // 29376 B
  const int t = threadIdx.x;
  const int wv = t >> 6, lane = t & 63;
  const int l31 = lane & 31, l5 = lane >> 5;
  const int rp = wv & 1, ntw = (wv >> 1) & 1, kh = wv >> 2;
  const int x0 = blockIdx.x * 32, y0 = blockIdx.y * 4, b = blockIdx.z;

  f32x16 acc[2] = {};
  float4 pa[4], pb[4];
  bf16x8 wfr[18];

  auto issueF = [&](int cc) {
    #pragma unroll
    for (int r = 0; r < 4; ++r) {
      const int i = t + r * 512;
      const float4 z = {0.f, 0.f, 0.f, 0.f};
      pa[r] = z; pb[r] = z;
      if (i < 1632) {
        const int px = i >> 3, gg = i & 7;
        const int ly = px / 34, lx = px - ly * 34;
        const int gy = y0 + ly - 1, gx = x0 + lx - 1;
        if ((unsigned)gy < 96u && (unsigned)gx < 96u) {
          const float* p = feat + ((size_t)((b * 96 + gy) * 96 + gx)) * 256
                           + cc * 64 + gg * 8;
          pa[r] = *(const float4*)p;
          pb[r] = *(const float4*)(p + 4);
        }
      }
    }
  };
  auto commitF = [&]() {
    #pragma unroll
    for (int r = 0; r < 4; ++r) {
      const int i = t + r * 512;
      if (i < 1632) {
        const int px = i >> 3, gg = i & 7;
        uint4 o;
        o.x = pk2(pa[r].x, pa[r].y); o.y = pk2(pa[r].z, pa[r].w);
        o.z = pk2(pb[r].x, pb[r].y); o.w = pk2(pb[r].z, pb[r].w);
        *(uint4*)(tile + px * 72 + gg * 8) = o;
      }
    }
  };
  auto loadW = [&](int cc) {
    #pragma unroll
    for (int tap = 0; tap < 9; ++tap)
      #pragma unroll
      for (int hh = 0; hh < 2; ++hh) {
        const int h = kh * 2 + hh;
        wfr[tap * 2 + hh] = *(const bf16x8*)(wcf +
            ((size_t)((((cc * 9 + tap) * 4 + h) * 2) + ntw)) * 512 + lane * 8);
      }
  };

  issueF(0);
  loadW(0);
  for (int cc = 0; cc < 4; ++cc) {
    __syncthreads();
    commitF();
    __syncthreads();
    if (cc < 3) issueF(cc + 1);
    #pragma unroll
    for (int tap = 0; tap < 9; ++tap) {
      const int dy = tap / 3, dx = tap - dy * 3;
      #pragma unroll
      for (int hh = 0; hh < 2; ++hh) {
        const bf16x8 bfr = wfr[tap * 2 + hh];
        #pragma unroll
        for (int ai = 0; ai < 2; ++ai) {
          const bf16x8 afr = *(const bf16x8*)(tile +
              ((rp * 2 + ai + dy) * 34 + l31 + dx) * 72
              + (kh * 2 + hh) * 16 + l5 * 8);
          acc[ai] = __builtin_amdgcn_mfma_f32_32x32x16_bf16(afr, bfr, acc[ai],
                                                            0, 0, 0);
        }
      }
    }
    if (cc < 3) loadW(cc + 1);
  }

  // coordinate channels: one K=16 step (ch0=xx, ch1=yy) -> kh==0 waves only
  bf16x8 wcr[9];
  if (kh == 0) {
    #pragma unroll
    for (int tap = 0; tap < 9; ++tap)
      wcr[tap] = *(const bf16x8*)(wcc + ((size_t)(tap * 2 + ntw)) * 512
                                  + lane * 8);
  }
  __syncthreads();
  for (int i = t; i < 408; i += 512) {
    const int px = i >> 1, gg = i & 1;
    const int ly = px / 34, lx = px - ly * 34;
    const int gy = y0 + ly - 1, gx = x0 + lx - 1;
    uint4 o = {0u, 0u, 0u, 0u};
    if (gg == 0 && (unsigned)gy < 96u && (unsigned)gx < 96u) {
      const float xx = -1.f + (2.f / 95.f) * (float)gx;
      const float yy = -1.f + (2.f / 95.f) * (float)gy;
      o.x = pk2(xx, yy);
    }
    *(uint4*)(tile + (ly * 34 + lx) * 72 + gg * 8) = o;
  }
  __syncthreads();
  if (kh == 0) {
    #pragma unroll
    for (int tap = 0; tap < 9; ++tap) {
      const int dy = tap / 3, dx = tap - dy * 3;
      #pragma unroll
      for (int ai = 0; ai < 2; ++ai) {
        const bf16x8 afr = *(const bf16x8*)(tile +
            ((rp * 2 + ai + dy) * 34 + l31 + dx) * 72 + l5 * 8);
        acc[ai] = __builtin_amdgcn_mfma_f32_32x32x16_bf16(afr, wcr[tap],
                                                          acc[ai], 0, 0, 0);
      }
    }
  }

  // kh reduction via LDS (tile is dead), two 16KB rounds
  float* redk = (float*)tile;
  const int slot = wv & 3;   // rp + 2*ntw
  #pragma unroll
  for (int ai = 0; ai < 2; ++ai) {
    __syncthreads();
    if (kh == 1) {
      #pragma unroll
      for (int r = 0; r < 16; ++r)
        redk[(r * 4 + slot) * 64 + lane] = acc[ai][r];
    }
    __syncthreads();
    if (kh == 0) {
      #pragma unroll
      for (int r = 0; r < 16; ++r)
        acc[ai][r] += redk[(r * 4 + slot) * 64 + lane];
    }
  }

  // epilogue: BN1 (+conv bias) + ReLU -> bf16   (kh==0 waves)
  if (kh == 0) {
    const int oc = ntw * 32 + l31;
    const float inv = g[oc] * rsqrtf(v[oc] + EPSBN);
    const float sh = bb[oc] - m[oc] * inv + cb[oc] * inv;
    #pragma unroll
    for (int ai = 0; ai < 2; ++ai) {
      const int y = y0 + rp * 2 + ai;
      #pragma unroll
      for (int r = 0; r < 16; ++r) {
        const int xr = (r & 3) + 8 * (r >> 2) + 4 * l5;
        const float val = fmaxf(fmaf(acc[ai][r], inv, sh), 0.f);
        x1b[((size_t)((b * 96 + y) * 96 + x0 + xr)) * 64 + oc] = f2bf(val);
      }
    }
  }
}

// ---------------------------------------------------------------------------
// 64->64ch 3x3 conv (bf16 NHWC64 in). Block 32x4 px, 512 thr, 8 waves.
// NN==2: waves = (rp, ntw, kh), 2 rows/wave, 18 frags preloaded to regs.
// NN==1 (offset conv): waves = (row, kh), 18 frags preloaded.
// kh partials reduced via LDS (tile reuse).
// EPI: 0 = BN+ReLU -> bf16 ; 1 = +bias -> fp32 NHWC18 ; 2 = BN+ReLU +
//      1x1 out conv + sigmoid -> fp32 (B,96,96).
// ---------------------------------------------------------------------------
template<int NN, int EPI>
__global__ __launch_bounds__(512, 2) void conv64_kernel(
    const u16* __restrict__ xin, const u16* __restrict__ wf,
    const float* __restrict__ bias,
    const float* __restrict__ g, const float* __restrict__ bb,
    const float* __restrict__ m, const float* __restrict__ v,
    const float* __restrict__ ow, const float* __restrict__ ob,
    void* __restrict__ outp)
{
  __shared__ __align__(16) u16 tile[6 * 34 * 72];
  __shared__ float red2[2][128];
  const int t = threadIdx.x;
  const int wv = t >> 6, lane = t & 63;
  const int l31 = lane & 31, l5 = lane >> 5;
  const int rp  = (NN == 2) ? (wv & 1) : 0;
  const int ntw = (NN == 2) ? ((wv >> 1) & 1) : 0;
  const int row = (NN == 2) ? 0 : (wv & 3);
  const int kh  = wv >> 2;
  const int x0 = blockIdx.x * 32, y0 = blockIdx.y * 4, b = blockIdx.z;

  // batch feature loads
  uint4 pf[4];
  #pragma unroll
  for (int r = 0; r < 4; ++r) {
    const int i = t + r * 512;
    const uint4 z = {0u, 0u, 0u, 0u};
    pf[r] = z;
    if (i < 1632) {
      const int px = i >> 3, gg = i & 7;
      const int ly = px / 34, lx = px - ly * 34;
      const int gy = y0 + ly - 1, gx = x0 + lx - 1;
      if ((unsigned)gy < 96u && (unsigned)gx < 96u)
        pf[r] = *(const uint4*)(xin + (((size_t)((b * 96 + gy) * 96 + gx)) << 6)
                                + gg * 8);
    }
  }
  // batch weight preload (in flight alongside features)
  bf16x8 wfr[18];
  #pragma unroll
  for (int tap = 0; tap < 9; ++tap)
    #pragma unroll
    for (int hh = 0; hh < 2; ++hh) {
      const int h = kh * 2 + hh;
      const size_t f = (NN == 2) ? (size_t)((tap * 4 + h) * 2 + ntw)
                                 : (size_t)(tap * 4 + h);
      wfr[tap * 2 + hh] = *(const bf16x8*)(wf + f * 512 + lane * 8);
    }
  #pragma unroll
  for (int r = 0; r < 4; ++r) {
    const int i = t + r * 512;
    if (i < 1632) {
      const int px = i >> 3, gg = i & 7;
      *(uint4*)(tile + px * 72 + gg * 8) = pf[r];
    }
  }
  __syncthreads();

  constexpr int NA = (NN == 2) ? 2 : 1;
  f32x16 acc[NA] = {};
  #pragma unroll
  for (int tap = 0; tap < 9; ++tap) {
    const int dy = tap / 3, dx = tap - dy * 3;
    #pragma unroll
    for (int hh = 0; hh < 2; ++hh) {
      const int h = kh * 2 + hh;
      #pragma unroll
      for (int ai = 0; ai < NA; ++ai) {
        const int rr = (NN == 2) ? (rp * 2 + ai) : row;
        const bf16x8 afr = *(const bf16x8*)(tile +
            ((rr + dy) * 34 + l31 + dx) * 72 + h * 16 + l5 * 8);
        acc[ai] = __builtin_amdgcn_mfma_f32_32x32x16_bf16(afr, wfr[tap * 2 + hh],
                                                          acc[ai], 0, 0, 0);
      }
    }
  }

  // kh reduction via LDS (tile reuse)
  float* redk = (float*)tile;
  const int slot = (NN == 2) ? (wv & 3) : row;
  #pragma unroll
  for (int ai = 0; ai < NA; ++ai) {
    __syncthreads();
    if (kh == 1) {
      #pragma unroll
      for (int r = 0; r < 16; ++r)
        redk[(r * 4 + slot) * 64 + lane] = acc[ai][r];
    }
    __syncthreads();
    if (kh == 0) {
      #pragma unroll
      for (int r = 0; r < 16; ++r)
        acc[ai][r] += redk[(r * 4 + slot) * 64 + lane];
    }
  }

  if constexpr (EPI == 0) {
    if (kh == 0) {
      u16* xo = (u16*)outp;
      const int oc = ntw * 32 + l31;
      const float inv = g[oc] * rsqrtf(v[oc] + EPSBN);
      const float sh = bb[oc] - m[oc] * inv;
      #pragma unroll
      for (int ai = 0; ai < NA; ++ai) {
        const int y = y0 + rp * 2 + ai;
        #pragma unroll
        for (int r = 0; r < 16; ++r) {
          const int xr = (r & 3) + 8 * (r >> 2) + 4 * l5;
          const float val = fmaxf(fmaf(acc[ai][r], inv, sh), 0.f);
          xo[((size_t)((b * 96 + y) * 96 + x0 + xr)) * 64 + oc] = f2bf(val);
        }
      }
    }
  } else if constexpr (EPI == 1) {
    if (kh == 0 && l31 < 18) {
      float* fo = (float*)outp;
      const int y = y0 + row;
      const float bs = bias[l31];
      #pragma unroll
      for (int r = 0; r < 16; ++r) {
        const int xr = (r & 3) + 8 * (r >> 2) + 4 * l5;
        fo[((size_t)((b * 96 + y) * 96 + x0 + xr)) * 18 + l31] = acc[0][r] + bs;
      }
    }
  } else {  // EPI == 2
    if (kh == 0) {
      const int oc = ntw * 32 + l31;
      const float inv = g[oc] * rsqrtf(v[oc] + EPSBN);
      const float sh = bb[oc] - m[oc] * inv;
      const float wo = ow[oc];
      #pragma unroll
      for (int ai = 0; ai < NA; ++ai) {
        float pr[16];
        #pragma unroll
        for (int r = 0; r < 16; ++r) {
          const float val = fmaxf(fmaf(acc[ai][r], inv, sh), 0.f);
          pr[r] = val * wo;
        }
        #pragma unroll
        for (int mask = 1; mask <= 16; mask <<= 1)
          #pragma unroll
          for (int r = 0; r < 16; ++r)
            pr[r] += __shfl_xor(pr[r], mask);
        if (l31 == 0) {
          #pragma unroll
          for (int r = 0; r < 16; ++r) {
            const int xr = (r & 3) + 8 * (r >> 2) + 4 * l5;
            red2[ntw][(rp * 2 + ai) * 32 + xr] = pr[r];
          }
        }
      }
    }
    __syncthreads();
    if (t < 128) {
      float* fo = (float*)outp;
      const int yy = y0 + (t >> 5), xx = x0 + (t & 31);
      const float val = red2[0][t] + red2[1][t] + ob[0];
      fo[(size_t)(b * 96 + yy) * 96 + xx] = 1.f / (1.f + expf(-val));
    }
  }
}

// ---------------------------------------------------------------------------
// Deformable conv 64->64 + BN2 + ReLU -> x2b. Block 16x8 px, 512 threads,
// 8 waves = (mt 0..3: 32-px M tile) x (ntw 0..1: oc tile).
// Double-buffered sample LDS; tap k+1 gathers issued before tap k MFMAs.
// (unchanged from round 4)
// ---------------------------------------------------------------------------
__global__ __launch_bounds__(512, 4) void deform_kernel(
    const u16* __restrict__ x1b, const float* __restrict__ off,
    const u16* __restrict__ wdf,
    const float* __restrict__ g, const float* __restrict__ bb,
    const float* __restrict__ m, const float* __restrict__ v,
    u16* __restrict__ x2b)
{
  __shared__ __align__(16) u16 s[2 * 128 * 72];   // 36864 B
  __shared__ float offs[128 * 18];                //  9216 B
  const int t = threadIdx.x;
  const int wv = t >> 6, lane = t & 63;
  const int l31 = lane & 31, l5 = lane >> 5;
  const int mt = wv & 3, ntw = wv >> 2;
  const int x0 = blockIdx.x * 16, y0 = blockIdx.y * 8, b = blockIdx.z;

  {
    float po[5];
    #pragma unroll
    for (int r = 0; r < 5; ++r) {
      const int i = t + r * 512;
      po[r] = 0.f;
      if (i < 2304) {
        const int p = i / 18, c = i - p * 18;
        const int gy = y0 + (p >> 4), gx = x0 + (p & 15);
        po[r] = off[((size_t)((b * 96 + gy) * 96 + gx)) * 18 + c];
      }
    }
    #pragma unroll
    for (int r = 0; r < 5; ++r) {
      const int i = t + r * 512;
      if (i < 2304) offs[i] = po[r];
    }
  }
  __syncthreads();

  const int sp = t >> 2, part = t & 3;
  const int sy = y0 + (sp >> 4), sx = x0 + (sp & 15);

  uint4 gbuf[8];
  float w4[4];

  auto prefetch = [&](int k) {
    const float oy = offs[sp * 18 + 2 * k];
    const float ox = offs[sp * 18 + 2 * k + 1];
    const float py = (float)(sy + k / 3 - 1) + oy;
    const float px = (float)(sx + k % 3 - 1) + ox;
    const float yf = floorf(py), xf = floorf(px);
    const float fy = py - yf, fx = px - xf;
    const int yi = (int)yf, xi = (int)xf;
    #pragma unroll
    for (int cor = 0; cor < 4; ++cor) {
      const int cy = yi + (cor >> 1), cx = xi + (cor & 1);
      const uint4 z = {0u, 0u, 0u, 0u};
      gbuf[2 * cor] = z; gbuf[2 * cor + 1] = z;
      const float wy = (cor & 2) ? fy : 1.f - fy;
      const float wx = (cor & 1) ? fx : 1.f - fx;
      w4[cor] = 0.f;
      if ((unsigned)cy < 96u && (unsigned)cx < 96u) {
        w4[cor] = wy * wx;
        const u16* p = x1b + ((size_t)((b * 96 + cy) * 96 + cx)) * 64
                       + part * 16;
        gbuf[2 * cor]     = *(const uint4*)p;
        gbuf[2 * cor + 1] = *(const uint4*)(p + 8);
      }
    }
  };
  auto combine = [&](u16* dst) {
    float val[16];
    #pragma unroll
    for (int j = 0; j < 16; ++j) val[j] = 0.f;
    #pragma unroll
    for (int cor = 0; cor < 4; ++cor) {
      const float wgt = w4[cor];
      const u32 uu[8] = {gbuf[2 * cor].x, gbuf[2 * cor].y,
                         gbuf[2 * cor].z, gbuf[2 * cor].w,
                         gbuf[2 * cor + 1].x, gbuf[2 * cor + 1].y,
                         gbuf[2 * cor + 1].z, gbuf[2 * cor + 1].w};
      #pragma unroll
      for (int u = 0; u < 8; ++u) {
        val[2 * u]     = fmaf(wgt, lo2f(uu[u]), val[2 * u]);
        val[2 * u + 1] = fmaf(wgt, hi2f(uu[u]), val[2 * u + 1]);
      }
    }
    u32 pk[8];
    #pragma unroll
    for (int u = 0; u < 8; ++u) pk[u] = pk2(val[2 * u], val[2 * u + 1]);
    uint4 w0 = {pk[0], pk[1], pk[2], pk[3]};
    uint4 w1 = {pk[4], pk[5], pk[6], pk[7]};
    *(uint4*)(dst + sp * 72 + part * 16) = w0;
    *(uint4*)(dst + sp * 72 + part * 16 + 8) = w1;
  };

  f32x16 acc = {};

  prefetch(0);
  combine(s);          // buffer 0
  __syncthreads();

  for (int k = 0; k < 9; ++k) {
    u16* cur = s + (k & 1) * 9216;
    if (k < 8) prefetch(k + 1);          // gathers fly during MFMAs
    #pragma unroll
    for (int h = 0; h < 4; ++h) {
      const bf16x8 afr = *(const bf16x8*)(cur + (mt * 32 + l31) * 72
                                          + h * 16 + l5 * 8);
      const bf16x8 bfr = *(const bf16x8*)(wdf +
          ((size_t)((k * 4 + h) * 2 + ntw)) * 512 + lane * 8);
      acc = __builtin_amdgcn_mfma_f32_32x32x16_bf16(afr, bfr, acc, 0, 0, 0);
    }
    if (k < 8) combine(s + ((k + 1) & 1) * 9216);
    __syncthreads();
  }

  const int oc = ntw * 32 + l31;
  const float inv = g[oc] * rsqrtf(v[oc] + EPSBN);
  const float sh = bb[oc] - m[oc] * inv;
  #pragma unroll
  for (int r = 0; r < 16; ++r) {
    const int pxi = mt * 32 + (r & 3) + 8 * (r >> 2) + 4 * l5;
    const int y = y0 + (pxi >> 4), x = x0 + (pxi & 15);
    const float val = fmaxf(fmaf(acc[r], inv, sh), 0.f);
    x2b[((size_t)((b * 96 + y) * 96 + x)) * 64 + oc] = f2bf(val);
  }
}

extern "C" void kernel_launch(void* const* d_in, const int* in_sizes, int n_in,
                              void* d_out, int out_size, void* d_ws,
                              size_t ws_size, hipStream_t stream)
{
  (void)in_sizes; (void)n_in; (void)out_size; (void)ws_size;
  const float* features = (const float*)d_in[0];
  const float* coord_w  = (const float*)d_in[1];
  const float* coord_b  = (const float*)d_in[2];
  const float* bn1g = (const float*)d_in[3];
  const float* bn1b = (const float*)d_in[4];
  const float* bn1m = (const float*)d_in[5];
  const float* bn1v = (const float*)d_in[6];
  const float* off_w = (const float*)d_in[7];
  const float* off_b = (const float*)d_in[8];
  const float* dc_w  = (const float*)d_in[9];
  const float* bn2g = (const float*)d_in[10];
  const float* bn2b = (const float*)d_in[11];
  const float* bn2m = (const float*)d_in[12];
  const float* bn2v = (const float*)d_in[13];
  const float* r1_w = (const float*)d_in[14];
  const float* bn3g = (const float*)d_in[15];
  const float* bn3b = (const float*)d_in[16];
  const float* bn3m = (const float*)d_in[17];
  const float* bn3v = (const float*)d_in[18];
  const float* r2_w = (const float*)d_in[19];
  const float* bn4g = (const float*)d_in[20];
  const float* bn4b = (const float*)d_in[21];
  const float* bn4m = (const float*)d_in[22];
  const float* bn4v = (const float*)d_in[23];
  const float* out_w = (const float*)d_in[24];
  const float* out_b = (const float*)d_in[25];

  char* W = (char*)d_ws;
  float* offb = (float*)W;                         //  5,308,416 B
  u16*   x1b  = (u16*)(W + 5308416);               //  9,437,184 B
  u16*   x2b  = (u16*)(W + 14745600);
  u16*   x3b  = (u16*)(W + 24182784);
  u16*   wcf  = (u16*)(W + 33619968);
  u16*   wcc  = wcf + N_WCF;
  u16*   wof  = wcc + N_WCC;
  u16*   wdf  = wof + N_WOF;
  u16*   wr1  = wdf + N_W64;
  u16*   wr2  = wr1 + N_W64;

  prep_kernel<<<(N_ALLW + 255) / 256, 256, 0, stream>>>(
      coord_w, off_w, dc_w, r1_w, r2_w, wcf, wcc, wof, wdf, wr1, wr2);

  dim3 grid(3, 24, 8);   // 32x4 tiles
  dim3 gridD(6, 12, 8);  // 16x8 tiles (deform)

  coord_conv_kernel<<<grid, 512, 0, stream>>>(
      features, wcf, wcc, coord_b, bn1g, bn1b, bn1m, bn1v, x1b);
  conv64_kernel<1, 1><<<grid, 512, 0, stream>>>(
      x1b, wof, off_b, nullptr, nullptr, nullptr, nullptr, nullptr, nullptr,
      (void*)offb);
  deform_kernel<<<gridD, 512, 0, stream>>>(
      x1b, offb, wdf, bn2g, bn2b, bn2m, bn2v, x2b);
  conv64_kernel<2, 0><<<grid, 512, 0, stream>>>(
      x2b, wr1, nullptr, bn3g, bn3b, bn3m, bn3v, nullptr, nullptr, (void*)x3b);
  conv64_kernel<2, 2><<<grid, 512, 0, stream>>>(
      x3b, wr2, nullptr, bn4g, bn4b, bn4m, bn4v, out_w, out_b, d_out);
}